// Round 3
// baseline (858.163 us; speedup 1.0000x reference)
//
#include <hip/hip_runtime.h>
#include <hip/hip_bf16.h>

#define T_TOK 1024
#define H_DIM 1024
#define I_DIM 1408
#define NE 16
#define NEP 18   // 16 routed + 2 pseudo (shared expert = two I=1408 halves)
#define BM 256   // token tile per block

typedef __attribute__((ext_vector_type(8))) __bf16 bf16x8;
typedef __attribute__((ext_vector_type(4))) float f32x4;

__device__ __forceinline__ bf16x8 cvt8(float4 a, float4 b) {
    bf16x8 r;
    r[0] = (__bf16)a.x; r[1] = (__bf16)a.y; r[2] = (__bf16)a.z; r[3] = (__bf16)a.w;
    r[4] = (__bf16)b.x; r[5] = (__bf16)b.y; r[6] = (__bf16)b.z; r[7] = (__bf16)b.w;
    return r;
}

// ---------------------------------------------------------------- gate ------
__global__ __launch_bounds__(64) void gate_kernel(
    const float* __restrict__ x, const float* __restrict__ gw,
    const float* __restrict__ gb,
    int* __restrict__ counts, int* __restrict__ etok, float* __restrict__ ew)
{
    const int t = blockIdx.x;
    const int lane = threadIdx.x;
    float s[NE];
#pragma unroll
    for (int e = 0; e < NE; ++e) s[e] = 0.f;
    const float* xr = x + (size_t)t * H_DIM;
    for (int i = lane; i < H_DIM; i += 64) {
        float xv = xr[i];
#pragma unroll
        for (int e = 0; e < NE; ++e) s[e] += xv * gw[e * H_DIM + i];
    }
#pragma unroll
    for (int e = 0; e < NE; ++e) {
        for (int off = 32; off > 0; off >>= 1) s[e] += __shfl_xor(s[e], off);
    }
    if (lane == 0) {
        float scores[NE], sfc[NE];
#pragma unroll
        for (int e = 0; e < NE; ++e) {
            scores[e] = 1.f / (1.f + __expf(-s[e]));
            sfc[e] = scores[e] + gb[e];
        }
        float gsc[4];
#pragma unroll
        for (int g = 0; g < 4; ++g) {
            float m1 = -1e30f, m2 = -1e30f;
#pragma unroll
            for (int j = 0; j < 4; ++j) {
                float v = sfc[4 * g + j];
                if (v > m1) { m2 = m1; m1 = v; } else if (v > m2) { m2 = v; }
            }
            gsc[g] = m1 + m2;
        }
        int g1 = 0;
        for (int g = 1; g < 4; ++g) if (gsc[g] > gsc[g1]) g1 = g;
        int g2 = -1;
        for (int g = 0; g < 4; ++g) {
            if (g == g1) continue;
            if (g2 < 0 || gsc[g] > gsc[g2]) g2 = g;
        }
        float tmp[NE];
#pragma unroll
        for (int e = 0; e < NE; ++e) {
            int gg = e >> 2;
            tmp[e] = (gg == g1 || gg == g2) ? sfc[e] : 0.0f;
        }
        int idxs[4]; float wk[4]; float wsum = 0.f;
#pragma unroll
        for (int k = 0; k < 4; ++k) {
            int bi = 0;
            for (int e = 1; e < NE; ++e) if (tmp[e] > tmp[bi]) bi = e;
            idxs[k] = bi; wk[k] = scores[bi]; wsum += scores[bi];
            tmp[bi] = -1e30f;
        }
        float inv = 1.f / (wsum + 1e-20f);
        for (int k = 0; k < 4; ++k) {
            int e = idxs[k];
            int pos = atomicAdd(&counts[e], 1);
            etok[e * T_TOK + pos] = t;
            ew[e * T_TOK + pos] = wk[k] * inv;   // SCALE = 1.0
        }
    }
}

// ---------------------------------------------------- x f32 -> bf16 ---------
__global__ __launch_bounds__(256) void cvtx_kernel(
    const float* __restrict__ x, __hip_bfloat16* __restrict__ x_bf)
{
    int i = (blockIdx.x * 256 + threadIdx.x) * 4;
    float4 v = ((const float4*)x)[i >> 2];
    x_bf[i + 0] = __float2bfloat16(v.x);
    x_bf[i + 1] = __float2bfloat16(v.y);
    x_bf[i + 2] = __float2bfloat16(v.z);
    x_bf[i + 3] = __float2bfloat16(v.w);
}

// ------------------------------------------------------------- gate/up ------
// Grid (22, ne, 4). Block = [BM=256 tok x 64 I-cols]; wave w owns 64 tokens.
// No LDS staging / no barriers in the main loop: each lane loads its own
// B fragment (8 f32, two dwordx4) straight from the fp32 weights and
// converts in registers. 4-wave redundancy is served by L1 (16 KB/step
// slice). Waves run unsynchronized -> TLP + compiler load hoisting hide
// global latency instead of a barrier-locked 1-step pipeline.
__global__ __launch_bounds__(256, 2) void gateup_kernel(
    const __hip_bfloat16* __restrict__ x_bf,
    const float* __restrict__ gproj, const float* __restrict__ uproj,
    const float* __restrict__ sgw, const float* __restrict__ suw,
    const int* __restrict__ counts, const int* __restrict__ etok,
    __hip_bfloat16* __restrict__ act, int e0)
{
    const int slot = blockIdx.y;
    const int e = e0 + slot;
    const int cnt = (e < NE) ? counts[e] : T_TOK;
    const int row0 = blockIdx.z * BM;
    if (row0 >= cnt) return;

    __shared__ int toks[BM];
    const int tid = threadIdx.x;
    {
        int r = row0 + tid;
        toks[tid] = (e < NE) ? ((r < cnt) ? etok[e * T_TOK + r] : 0) : r;
    }
    __syncthreads();   // toks visible; only barrier in the kernel

    const int nb0 = blockIdx.x * 64;
    const float *wg, *wu;
    if (e < NE) {
        wg = gproj + (size_t)e * I_DIM * H_DIM;
        wu = uproj + (size_t)e * I_DIM * H_DIM;
    } else {
        wg = sgw + (size_t)(e - NE) * I_DIM * H_DIM;
        wu = suw + (size_t)(e - NE) * I_DIM * H_DIM;
    }

    const int lane = tid & 63;
    const int w = tid >> 6;
    const int col = lane & 15, kq = lane >> 4;

    const __hip_bfloat16* ar[4];
#pragma unroll
    for (int mi = 0; mi < 4; ++mi)
        ar[mi] = x_bf + (size_t)toks[w * 64 + mi * 16 + col] * H_DIM + kq * 8;

    const float* brg[4];
    const float* bru[4];
#pragma unroll
    for (int ni = 0; ni < 4; ++ni) {
        brg[ni] = wg + (size_t)(nb0 + ni * 16 + col) * H_DIM + kq * 8;
        bru[ni] = wu + (size_t)(nb0 + ni * 16 + col) * H_DIM + kq * 8;
    }

    f32x4 accg[4][4], accu[4][4];
#pragma unroll
    for (int mi = 0; mi < 4; ++mi)
#pragma unroll
        for (int ni = 0; ni < 4; ++ni) {
            accg[mi][ni] = (f32x4){0.f, 0.f, 0.f, 0.f};
            accu[mi][ni] = (f32x4){0.f, 0.f, 0.f, 0.f};
        }

#pragma unroll 2
    for (int k = 0; k < 32; ++k) {
        bf16x8 a[4], bg[4], bu[4];
#pragma unroll
        for (int mi = 0; mi < 4; ++mi) a[mi] = *(const bf16x8*)(ar[mi] + k * 32);
#pragma unroll
        for (int ni = 0; ni < 4; ++ni) {
            const float4* pg = (const float4*)(brg[ni] + k * 32);
            const float4* pu = (const float4*)(bru[ni] + k * 32);
            float4 g0 = pg[0], g1 = pg[1];
            float4 u0 = pu[0], u1 = pu[1];
            bg[ni] = cvt8(g0, g1);
            bu[ni] = cvt8(u0, u1);
        }
#pragma unroll
        for (int mi = 0; mi < 4; ++mi)
#pragma unroll
            for (int ni = 0; ni < 4; ++ni) {
                accg[mi][ni] = __builtin_amdgcn_mfma_f32_16x16x32_bf16(a[mi], bg[ni], accg[mi][ni], 0, 0, 0);
                accu[mi][ni] = __builtin_amdgcn_mfma_f32_16x16x32_bf16(a[mi], bu[ni], accu[mi][ni], 0, 0, 0);
            }
    }

    // epilogue: silu(g)*u -> act (zeros for padded rows so down reads zeros)
#pragma unroll
    for (int mi = 0; mi < 4; ++mi)
#pragma unroll
        for (int ni = 0; ni < 4; ++ni)
#pragma unroll
            for (int r = 0; r < 4; ++r) {
                int lrow = w * 64 + mi * 16 + kq * 4 + r;
                int grow = row0 + lrow;
                float g = accg[mi][ni][r];
                float a = (grow < cnt) ? (g / (1.f + __expf(-g)) * accu[mi][ni][r]) : 0.f;
                act[((size_t)slot * T_TOK + grow) * I_DIM + nb0 + ni * 16 + col] =
                    __float2bfloat16(a);
            }
}

// ---------------------------------------------------------------- down ------
// Grid (16, ne, 4). Block = [BM=256 act-rows x 64 H-cols]; K = I_DIM = 44*32.
// Same barrier-free direct-load structure; lighter acc (64 f32) so ask for
// 3 waves/SIMD.
__global__ __launch_bounds__(256, 3) void down_kernel(
    const __hip_bfloat16* __restrict__ act,
    const float* __restrict__ dproj, const float* __restrict__ sdw,
    const int* __restrict__ counts, const int* __restrict__ etok,
    const float* __restrict__ ew, float* __restrict__ y, int e0)
{
    const int slot = blockIdx.y;
    const int e = e0 + slot;
    const int cnt = (e < NE) ? counts[e] : T_TOK;
    const int row0 = blockIdx.z * BM;
    if (row0 >= cnt) return;

    __shared__ int toks[BM];
    __shared__ float wts[BM];

    const int tid = threadIdx.x;
    {
        int r = row0 + tid;
        if (e < NE) {
            bool ok = r < cnt;
            toks[tid] = ok ? etok[e * T_TOK + r] : 0;
            wts[tid]  = ok ? ew[e * T_TOK + r] : 0.f;
        } else { toks[tid] = r; wts[tid] = 1.f; }
    }
    __syncthreads();

    const int nb0 = blockIdx.x * 64;
    const float* wd;
    int wstride;
    if (e < NE) { wd = dproj + (size_t)e * H_DIM * I_DIM; wstride = I_DIM; }
    else        { wd = sdw + (size_t)(e - NE) * I_DIM;    wstride = 2 * I_DIM; }

    const int lane = tid & 63;
    const int w = tid >> 6;
    const int col = lane & 15, kq = lane >> 4;

    const __hip_bfloat16* ar[4];
#pragma unroll
    for (int mi = 0; mi < 4; ++mi)
        ar[mi] = act + ((size_t)slot * T_TOK + row0 + w * 64 + mi * 16 + col) * I_DIM + kq * 8;

    const float* brd[4];
#pragma unroll
    for (int ni = 0; ni < 4; ++ni)
        brd[ni] = wd + (size_t)(nb0 + ni * 16 + col) * wstride + kq * 8;

    f32x4 acc[4][4];
#pragma unroll
    for (int mi = 0; mi < 4; ++mi)
#pragma unroll
        for (int ni = 0; ni < 4; ++ni) acc[mi][ni] = (f32x4){0.f, 0.f, 0.f, 0.f};

#pragma unroll 2
    for (int k = 0; k < I_DIM / 32; ++k) {
        bf16x8 a[4], b[4];
#pragma unroll
        for (int mi = 0; mi < 4; ++mi) a[mi] = *(const bf16x8*)(ar[mi] + k * 32);
#pragma unroll
        for (int ni = 0; ni < 4; ++ni) {
            const float4* pd = (const float4*)(brd[ni] + k * 32);
            float4 d0 = pd[0], d1 = pd[1];
            b[ni] = cvt8(d0, d1);
        }
#pragma unroll
        for (int mi = 0; mi < 4; ++mi)
#pragma unroll
            for (int ni = 0; ni < 4; ++ni)
                acc[mi][ni] = __builtin_amdgcn_mfma_f32_16x16x32_bf16(a[mi], b[ni], acc[mi][ni], 0, 0, 0);
    }

#pragma unroll
    for (int mi = 0; mi < 4; ++mi)
#pragma unroll
        for (int ni = 0; ni < 4; ++ni)
#pragma unroll
            for (int r = 0; r < 4; ++r) {
                int lrow = w * 64 + mi * 16 + kq * 4 + r;
                int grow = row0 + lrow;
                if (grow < cnt)
                    atomicAdd(&y[(size_t)toks[lrow] * H_DIM + nb0 + ni * 16 + col],
                              acc[mi][ni][r] * wts[lrow]);
            }
}

// -------------------------------------------------------------- launch ------
extern "C" void kernel_launch(void* const* d_in, const int* in_sizes, int n_in,
                              void* d_out, int out_size, void* d_ws, size_t ws_size,
                              hipStream_t stream) {
    (void)in_sizes; (void)n_in; (void)out_size;
    const float* x  = (const float*)d_in[0];
    const float* gw = (const float*)d_in[1];
    const float* gb = (const float*)d_in[2];
    const float* gp = (const float*)d_in[3];
    const float* up = (const float*)d_in[4];
    const float* dp = (const float*)d_in[5];
    const float* sg = (const float*)d_in[6];
    const float* su = (const float*)d_in[7];
    const float* sd = (const float*)d_in[8];
    float* out = (float*)d_out;

    char* ws = (char*)d_ws;
    int*   counts = (int*)ws;                                    // @0      (64 B)
    int*   etok   = (int*)(ws + 256);                            // 64 KB
    float* ew     = (float*)(ws + 256 + 65536);                  // 64 KB
    __hip_bfloat16* x_bf = (__hip_bfloat16*)(ws + 131328);       // 2 MB
    __hip_bfloat16* act  = (__hip_bfloat16*)(ws + 2228480);      // up to ~52 MB

    size_t fixed = 2228480;
    size_t per_e = (size_t)T_TOK * I_DIM * 2;                    // 2.75 MB / slot
    int cap = NEP;
    if (ws_size < fixed + (size_t)NEP * per_e) {
        cap = (ws_size > fixed + per_e) ? (int)((ws_size - fixed) / per_e) : 1;
        if (cap < 1) cap = 1;
    }

    hipMemsetAsync(ws, 0, 256, stream);                          // counts
    hipMemsetAsync(out, 0, (size_t)T_TOK * H_DIM * 4, stream);   // d_out is poisoned

    gate_kernel<<<dim3(T_TOK), dim3(64), 0, stream>>>(x, gw, gb, counts, etok, ew);
    cvtx_kernel<<<dim3(1024), dim3(256), 0, stream>>>(x, x_bf);

    for (int e0 = 0; e0 < NEP; e0 += cap) {
        int ne = NEP - e0 < cap ? NEP - e0 : cap;
        gateup_kernel<<<dim3(I_DIM / 64, ne, T_TOK / BM), dim3(256), 0, stream>>>(
            x_bf, gp, up, sg, su, counts, etok, act, e0);
        down_kernel<<<dim3(H_DIM / 64, ne, T_TOK / BM), dim3(256), 0, stream>>>(
            act, dp, sd, counts, etok, ew, out, e0);
    }
}

// Round 4
// 487.957 us; speedup vs baseline: 1.7587x; 1.7587x over previous
//
#include <hip/hip_runtime.h>
#include <hip/hip_bf16.h>

#define T_TOK 1024
#define H_DIM 1024
#define I_DIM 1408
#define NE 16
#define NEP 18   // 16 routed + 2 pseudo (shared expert = two I=1408 halves)
#define BM 256   // token tile per block
#define LDB 40   // padded LDS row (32 K bf16 + 8 pad) -> 2-way bank alias only

typedef __attribute__((ext_vector_type(8))) __bf16 bf16x8;
typedef __attribute__((ext_vector_type(4))) float f32x4;

__device__ __forceinline__ bf16x8 cvt8(float4 a, float4 b) {
    bf16x8 r;
    r[0] = (__bf16)a.x; r[1] = (__bf16)a.y; r[2] = (__bf16)a.z; r[3] = (__bf16)a.w;
    r[4] = (__bf16)b.x; r[5] = (__bf16)b.y; r[6] = (__bf16)b.z; r[7] = (__bf16)b.w;
    return r;
}

// ---------------------------------------------------------------- gate ------
__global__ __launch_bounds__(64) void gate_kernel(
    const float* __restrict__ x, const float* __restrict__ gw,
    const float* __restrict__ gb,
    int* __restrict__ counts, int* __restrict__ etok, float* __restrict__ ew)
{
    const int t = blockIdx.x;
    const int lane = threadIdx.x;
    float s[NE];
#pragma unroll
    for (int e = 0; e < NE; ++e) s[e] = 0.f;
    const float* xr = x + (size_t)t * H_DIM;
    for (int i = lane; i < H_DIM; i += 64) {
        float xv = xr[i];
#pragma unroll
        for (int e = 0; e < NE; ++e) s[e] += xv * gw[e * H_DIM + i];
    }
#pragma unroll
    for (int e = 0; e < NE; ++e) {
        for (int off = 32; off > 0; off >>= 1) s[e] += __shfl_xor(s[e], off);
    }
    if (lane == 0) {
        float scores[NE], sfc[NE];
#pragma unroll
        for (int e = 0; e < NE; ++e) {
            scores[e] = 1.f / (1.f + __expf(-s[e]));
            sfc[e] = scores[e] + gb[e];
        }
        float gsc[4];
#pragma unroll
        for (int g = 0; g < 4; ++g) {
            float m1 = -1e30f, m2 = -1e30f;
#pragma unroll
            for (int j = 0; j < 4; ++j) {
                float v = sfc[4 * g + j];
                if (v > m1) { m2 = m1; m1 = v; } else if (v > m2) { m2 = v; }
            }
            gsc[g] = m1 + m2;
        }
        int g1 = 0;
        for (int g = 1; g < 4; ++g) if (gsc[g] > gsc[g1]) g1 = g;
        int g2 = -1;
        for (int g = 0; g < 4; ++g) {
            if (g == g1) continue;
            if (g2 < 0 || gsc[g] > gsc[g2]) g2 = g;
        }
        float tmp[NE];
#pragma unroll
        for (int e = 0; e < NE; ++e) {
            int gg = e >> 2;
            tmp[e] = (gg == g1 || gg == g2) ? sfc[e] : 0.0f;
        }
        int idxs[4]; float wk[4]; float wsum = 0.f;
#pragma unroll
        for (int k = 0; k < 4; ++k) {
            int bi = 0;
            for (int e = 1; e < NE; ++e) if (tmp[e] > tmp[bi]) bi = e;
            idxs[k] = bi; wk[k] = scores[bi]; wsum += scores[bi];
            tmp[bi] = -1e30f;
        }
        float inv = 1.f / (wsum + 1e-20f);
        for (int k = 0; k < 4; ++k) {
            int e = idxs[k];
            int pos = atomicAdd(&counts[e], 1);
            etok[e * T_TOK + pos] = t;
            ew[e * T_TOK + pos] = wk[k] * inv;   // SCALE = 1.0
        }
    }
}

// ---------------------------------------------------- x f32 -> bf16 ---------
__global__ __launch_bounds__(256) void cvtx_kernel(
    const float* __restrict__ x, __hip_bfloat16* __restrict__ x_bf)
{
    int i = (blockIdx.x * 256 + threadIdx.x) * 4;
    float4 v = ((const float4*)x)[i >> 2];
    x_bf[i + 0] = __float2bfloat16(v.x);
    x_bf[i + 1] = __float2bfloat16(v.y);
    x_bf[i + 2] = __float2bfloat16(v.z);
    x_bf[i + 3] = __float2bfloat16(v.w);
}

// ------------------------------------------------------------- gate/up ------
// Grid (22, ne, 4). Block = [BM=256 tok x 64 I-cols]; wave w owns 64 tokens.
// 4-deep LDS ring, ONE raw barrier per K-step (lgkmcnt(0) + s_barrier +
// sched_barrier(0)). Staging loads for k+2 issued at step k stay in flight
// ACROSS barriers (compiler emits counted vmcnt for the cvt dependence) —
// unlike __syncthreads, which drains vmcnt(0) every step.
__global__ __launch_bounds__(256, 2) void gateup_kernel(
    const __hip_bfloat16* __restrict__ x_bf,
    const float* __restrict__ gproj, const float* __restrict__ uproj,
    const float* __restrict__ sgw, const float* __restrict__ suw,
    const int* __restrict__ counts, const int* __restrict__ etok,
    __hip_bfloat16* __restrict__ act, int e0)
{
    const int slot = blockIdx.y;
    const int e = e0 + slot;
    const int cnt = (e < NE) ? counts[e] : T_TOK;
    const int row0 = blockIdx.z * BM;
    if (row0 >= cnt) return;

    __shared__ int toks[BM];
    __shared__ __align__(16) __hip_bfloat16 Bg[4][64 * LDB];
    __shared__ __align__(16) __hip_bfloat16 Bu[4][64 * LDB];

    const int tid = threadIdx.x;
    {
        int r = row0 + tid;
        toks[tid] = (e < NE) ? ((r < cnt) ? etok[e * T_TOK + r] : 0) : r;
    }

    const int nb0 = blockIdx.x * 64;
    const float *wg, *wu;
    if (e < NE) {
        wg = gproj + (size_t)e * I_DIM * H_DIM;
        wu = uproj + (size_t)e * I_DIM * H_DIM;
    } else {
        wg = sgw + (size_t)(e - NE) * I_DIM * H_DIM;
        wu = suw + (size_t)(e - NE) * I_DIM * H_DIM;
    }
    // staging: thread -> (scol = tid>>2, sq = tid&3), 8 f32 each matrix
    const int scol = tid >> 2, sq = tid & 3;
    const float* sgp = wg + (size_t)(nb0 + scol) * H_DIM + sq * 8;
    const float* sup = wu + (size_t)(nb0 + scol) * H_DIM + sq * 8;
    const int lws = scol * LDB + sq * 8;   // lds write offset (bf16 elems)

    const int lane = tid & 63;
    const int w = tid >> 6;
    const int col = lane & 15, kq = lane >> 4;

    __syncthreads();   // toks visible (before any staging loads are issued)

    const __hip_bfloat16* ar[4];
#pragma unroll
    for (int mi = 0; mi < 4; ++mi)
        ar[mi] = x_bf + (size_t)toks[w * 64 + mi * 16 + col] * H_DIM + kq * 8;

    f32x4 accg[4][4], accu[4][4];
#pragma unroll
    for (int mi = 0; mi < 4; ++mi)
#pragma unroll
        for (int ni = 0; ni < 4; ++ni) {
            accg[mi][ni] = (f32x4){0.f, 0.f, 0.f, 0.f};
            accu[mi][ni] = (f32x4){0.f, 0.f, 0.f, 0.f};
        }

    // prologue: data for k=0 and k=1; write k=0 into ring buf 0
    float4 S0[4], S1[4];
    S0[0] = ((const float4*)sgp)[0]; S0[1] = ((const float4*)sgp)[1];
    S0[2] = ((const float4*)sup)[0]; S0[3] = ((const float4*)sup)[1];
    {
        const float* pg = sgp + 32; const float* pu = sup + 32;
        S1[0] = ((const float4*)pg)[0]; S1[1] = ((const float4*)pg)[1];
        S1[2] = ((const float4*)pu)[0]; S1[3] = ((const float4*)pu)[1];
    }
    *(bf16x8*)&Bg[0][lws] = cvt8(S0[0], S0[1]);
    *(bf16x8*)&Bu[0][lws] = cvt8(S0[2], S0[3]);

    // one step: W-phase (A loads, stage k+2, write k+1) | barrier | R-phase
    auto gu_step = [&](int k, float4 (&wrS)[4], float4 (&ldS)[4],
                       bool doStage, bool doWrite) {
        bf16x8 a[4];
#pragma unroll
        for (int mi = 0; mi < 4; ++mi) a[mi] = *(const bf16x8*)(ar[mi] + k * 32);
        if (doStage) {
            const float* pg = sgp + (k + 2) * 32;
            const float* pu = sup + (k + 2) * 32;
            ldS[0] = ((const float4*)pg)[0]; ldS[1] = ((const float4*)pg)[1];
            ldS[2] = ((const float4*)pu)[0]; ldS[3] = ((const float4*)pu)[1];
        }
        if (doWrite) {
            const int bw = (k + 1) & 3;
            *(bf16x8*)&Bg[bw][lws] = cvt8(wrS[0], wrS[1]);
            *(bf16x8*)&Bu[bw][lws] = cvt8(wrS[2], wrS[3]);
        }
        asm volatile("s_waitcnt lgkmcnt(0)" ::: "memory");  // writes visible
        __builtin_amdgcn_s_barrier();                        // no vmcnt drain
        __builtin_amdgcn_sched_barrier(0);                   // no hoist past bar
        const int br = k & 3;
        bf16x8 bg[4], bu[4];
#pragma unroll
        for (int ni = 0; ni < 4; ++ni) {
            bg[ni] = *(const bf16x8*)&Bg[br][(ni * 16 + col) * LDB + kq * 8];
            bu[ni] = *(const bf16x8*)&Bu[br][(ni * 16 + col) * LDB + kq * 8];
        }
#pragma unroll
        for (int mi = 0; mi < 4; ++mi)
#pragma unroll
            for (int ni = 0; ni < 4; ++ni) {
                accg[mi][ni] = __builtin_amdgcn_mfma_f32_16x16x32_bf16(a[mi], bg[ni], accg[mi][ni], 0, 0, 0);
                accu[mi][ni] = __builtin_amdgcn_mfma_f32_16x16x32_bf16(a[mi], bu[ni], accu[mi][ni], 0, 0, 0);
            }
    };

    for (int k = 0; k < 32; k += 2) {
        gu_step(k,     S1, S0, k + 2 < 32, true);        // write k+1, stage k+2
        gu_step(k + 1, S0, S1, k + 3 < 32, k + 2 < 32);  // write k+2, stage k+3
    }

    // epilogue: silu(g)*u -> act (zeros for padded rows so down reads zeros)
#pragma unroll
    for (int mi = 0; mi < 4; ++mi)
#pragma unroll
        for (int ni = 0; ni < 4; ++ni)
#pragma unroll
            for (int r = 0; r < 4; ++r) {
                int lrow = w * 64 + mi * 16 + kq * 4 + r;
                int grow = row0 + lrow;
                float g = accg[mi][ni][r];
                float a = (grow < cnt) ? (g / (1.f + __expf(-g)) * accu[mi][ni][r]) : 0.f;
                act[((size_t)slot * T_TOK + grow) * I_DIM + nb0 + ni * 16 + col] =
                    __float2bfloat16(a);
            }
}

// ---------------------------------------------------------------- down ------
// 1-D grid, XCD-clustered: all 16 nb-blocks of one (slot,z) group share the
// same 704KB act slice; mapping hw%8 == group%8 puts them on one XCD's L2.
// Same 4-deep ring / single-raw-barrier K-loop; K = I_DIM/32 = 44 steps.
__global__ __launch_bounds__(256, 3) void down_kernel(
    const __hip_bfloat16* __restrict__ act,
    const float* __restrict__ dproj, const float* __restrict__ sdw,
    const int* __restrict__ counts, const int* __restrict__ etok,
    const float* __restrict__ ew, float* __restrict__ y, int e0, int ne)
{
    const int hw = blockIdx.x;
    const int c = hw & 7, t = hw >> 3;
    const int nbt = t & 15, gh = t >> 4;
    const int g = c + 8 * gh;
    if (g >= ne * 4) return;           // Gp padding
    const int slot = g % ne;
    const int z = g / ne;

    const int e = e0 + slot;
    const int cnt = (e < NE) ? counts[e] : T_TOK;
    const int row0 = z * BM;
    if (row0 >= cnt) return;

    __shared__ int toks[BM];
    __shared__ float wts[BM];
    __shared__ __align__(16) __hip_bfloat16 Bd[4][64 * LDB];

    const int tid = threadIdx.x;
    {
        int r = row0 + tid;
        if (e < NE) {
            bool ok = r < cnt;
            toks[tid] = ok ? etok[e * T_TOK + r] : 0;
            wts[tid]  = ok ? ew[e * T_TOK + r] : 0.f;
        } else { toks[tid] = r; wts[tid] = 1.f; }
    }

    const int nb0 = nbt * 64;
    const float* wd;
    int wstride;
    if (e < NE) { wd = dproj + (size_t)e * H_DIM * I_DIM; wstride = I_DIM; }
    else        { wd = sdw + (size_t)(e - NE) * I_DIM;    wstride = 2 * I_DIM; }
    const int scol = tid >> 2, sq = tid & 3;
    const float* sdp = wd + (size_t)(nb0 + scol) * wstride + sq * 8;
    const int lws = scol * LDB + sq * 8;

    const int lane = tid & 63;
    const int w = tid >> 6;
    const int col = lane & 15, kq = lane >> 4;

    __syncthreads();   // toks/wts visible

    const __hip_bfloat16* ar[4];
#pragma unroll
    for (int mi = 0; mi < 4; ++mi)
        ar[mi] = act + ((size_t)slot * T_TOK + row0 + w * 64 + mi * 16 + col) * I_DIM + kq * 8;

    f32x4 acc[4][4];
#pragma unroll
    for (int mi = 0; mi < 4; ++mi)
#pragma unroll
        for (int ni = 0; ni < 4; ++ni) acc[mi][ni] = (f32x4){0.f, 0.f, 0.f, 0.f};

    float4 S0[2], S1[2];
    S0[0] = ((const float4*)sdp)[0]; S0[1] = ((const float4*)sdp)[1];
    {
        const float* pd = sdp + 32;
        S1[0] = ((const float4*)pd)[0]; S1[1] = ((const float4*)pd)[1];
    }
    *(bf16x8*)&Bd[0][lws] = cvt8(S0[0], S0[1]);

    auto d_step = [&](int k, float4 (&wrS)[2], float4 (&ldS)[2],
                      bool doStage, bool doWrite) {
        bf16x8 a[4];
#pragma unroll
        for (int mi = 0; mi < 4; ++mi) a[mi] = *(const bf16x8*)(ar[mi] + k * 32);
        if (doStage) {
            const float* pd = sdp + (k + 2) * 32;
            ldS[0] = ((const float4*)pd)[0]; ldS[1] = ((const float4*)pd)[1];
        }
        if (doWrite) {
            const int bw = (k + 1) & 3;
            *(bf16x8*)&Bd[bw][lws] = cvt8(wrS[0], wrS[1]);
        }
        asm volatile("s_waitcnt lgkmcnt(0)" ::: "memory");
        __builtin_amdgcn_s_barrier();
        __builtin_amdgcn_sched_barrier(0);
        const int br = k & 3;
        bf16x8 b[4];
#pragma unroll
        for (int ni = 0; ni < 4; ++ni)
            b[ni] = *(const bf16x8*)&Bd[br][(ni * 16 + col) * LDB + kq * 8];
#pragma unroll
        for (int mi = 0; mi < 4; ++mi)
#pragma unroll
            for (int ni = 0; ni < 4; ++ni)
                acc[mi][ni] = __builtin_amdgcn_mfma_f32_16x16x32_bf16(a[mi], b[ni], acc[mi][ni], 0, 0, 0);
    };

    const int KS = I_DIM / 32;   // 44
    for (int k = 0; k < KS; k += 2) {
        d_step(k,     S1, S0, k + 2 < KS, true);
        d_step(k + 1, S0, S1, k + 3 < KS, k + 2 < KS);
    }

#pragma unroll
    for (int mi = 0; mi < 4; ++mi)
#pragma unroll
        for (int ni = 0; ni < 4; ++ni)
#pragma unroll
            for (int r = 0; r < 4; ++r) {
                int lrow = w * 64 + mi * 16 + kq * 4 + r;
                int grow = row0 + lrow;
                if (grow < cnt)
                    atomicAdd(&y[(size_t)toks[lrow] * H_DIM + nb0 + ni * 16 + col],
                              acc[mi][ni][r] * wts[lrow]);
            }
}

// -------------------------------------------------------------- launch ------
extern "C" void kernel_launch(void* const* d_in, const int* in_sizes, int n_in,
                              void* d_out, int out_size, void* d_ws, size_t ws_size,
                              hipStream_t stream) {
    (void)in_sizes; (void)n_in; (void)out_size;
    const float* x  = (const float*)d_in[0];
    const float* gw = (const float*)d_in[1];
    const float* gb = (const float*)d_in[2];
    const float* gp = (const float*)d_in[3];
    const float* up = (const float*)d_in[4];
    const float* dp = (const float*)d_in[5];
    const float* sg = (const float*)d_in[6];
    const float* su = (const float*)d_in[7];
    const float* sd = (const float*)d_in[8];
    float* out = (float*)d_out;

    char* ws = (char*)d_ws;
    int*   counts = (int*)ws;                                    // @0      (64 B)
    int*   etok   = (int*)(ws + 256);                            // 64 KB
    float* ew     = (float*)(ws + 256 + 65536);                  // 64 KB
    __hip_bfloat16* x_bf = (__hip_bfloat16*)(ws + 131328);       // 2 MB
    __hip_bfloat16* act  = (__hip_bfloat16*)(ws + 2228480);      // up to ~52 MB

    size_t fixed = 2228480;
    size_t per_e = (size_t)T_TOK * I_DIM * 2;                    // 2.75 MB / slot
    int cap = NEP;
    if (ws_size < fixed + (size_t)NEP * per_e) {
        cap = (ws_size > fixed + per_e) ? (int)((ws_size - fixed) / per_e) : 1;
        if (cap < 1) cap = 1;
    }

    hipMemsetAsync(ws, 0, 256, stream);                          // counts
    hipMemsetAsync(out, 0, (size_t)T_TOK * H_DIM * 4, stream);   // d_out is poisoned

    gate_kernel<<<dim3(T_TOK), dim3(64), 0, stream>>>(x, gw, gb, counts, etok, ew);
    cvtx_kernel<<<dim3(1024), dim3(256), 0, stream>>>(x, x_bf);

    for (int e0 = 0; e0 < NEP; e0 += cap) {
        int ne = NEP - e0 < cap ? NEP - e0 : cap;
        gateup_kernel<<<dim3(I_DIM / 64, ne, T_TOK / BM), dim3(256), 0, stream>>>(
            x_bf, gp, up, sg, su, counts, etok, act, e0);
        int Gp = ((ne * 4 + 7) / 8) * 8;                         // XCD-bijective pad
        down_kernel<<<dim3(16 * Gp), dim3(256), 0, stream>>>(
            act, dp, sd, counts, etok, ew, out, e0, ne);
    }
}